// Round 24
// baseline (200.096 us; speedup 1.0000x reference)
//
#include <hip/hip_runtime.h>
#include <hip/hip_bf16.h>

typedef __attribute__((ext_vector_type(8))) short bf16x8;
typedef __attribute__((ext_vector_type(4))) float f32x4;
typedef __attribute__((ext_vector_type(4))) unsigned u32x4;

#define NEG 0.2f
#define CST 108         // 216 B row stride: 54 dw, gcd(54,32)=2 -> 16 bank starts
#define HSTRIDE 12288   // padded bf16 elems per head in d_ws
#define HCHUNKS 1512    // real 16B chunks per head image (112*216/16)
#define SASOFF 24192
#define SADOFF 24640
#define POFF   25088    // P image: 24192 B; pad 49280..49663 zeroed at init

__device__ __forceinline__ float lrelu(float x) { return x >= 0.0f ? x : NEG * x; }

__device__ __forceinline__ unsigned pk2(float a, float b) {
    __hip_bfloat162 h = __float22bfloat162_rn(float2{a, b});
    unsigned r;
    __builtin_memcpy(&r, &h, sizeof(r));
    return r;
}
__device__ __forceinline__ float bflo(unsigned u) {
    unsigned v = u << 16; float f; __builtin_memcpy(&f, &v, 4); return f;
}
__device__ __forceinline__ float bfhi(unsigned u) {
    unsigned v = u & 0xffff0000u; float f; __builtin_memcpy(&f, &v, 4); return f;
}
// 16B fragment as two 8B LDS reads (rows 8B- but not 16B-aligned)
__device__ __forceinline__ bf16x8 ld8(const unsigned short* p) {
    uint2 lo, hi;
    __builtin_memcpy(&lo, p, 8);
    __builtin_memcpy(&hi, p + 4, 8);
    u32x4 uv;
    uv.x = lo.x; uv.y = lo.y; uv.z = hi.x; uv.w = hi.y;
    return __builtin_bit_cast(bf16x8, uv);
}

// ---- prep (fast): Wp[h] = [112][108] bf16 image + exact zeroed tail ----
extern "C" __global__ void prep_w(const float* __restrict__ W,
                                  const float* __restrict__ att_src,
                                  const float* __restrict__ att_dst,
                                  unsigned short* __restrict__ Wp)
{
    __shared__ float red[2][4][128];
    __shared__ float sWS[128], sWD[128];
    const int h = blockIdx.x, tid = threadIdx.x;
    const int f = tid & 127, og = tid >> 7;
    const float* __restrict__ Wh = W + h * 10000;
    float ws = 0.0f, wd = 0.0f;
    if (f < 100) {
        for (int o = og * 25; o < og * 25 + 25; ++o) {
            float wv = Wh[o * 100 + f];
            ws = fmaf(att_src[h * 100 + o], wv, ws);
            wd = fmaf(att_dst[h * 100 + o], wv, wd);
        }
    }
    red[0][og][f] = ws;
    red[1][og][f] = wd;
    __syncthreads();
    if (tid < 256) {
        const int which = tid >> 7, ff = tid & 127;
        float s = (red[which][0][ff] + red[which][1][ff]) +
                  (red[which][2][ff] + red[which][3][ff]);
        (which ? sWD : sWS)[ff] = s;
    }
    __syncthreads();
    unsigned short* __restrict__ D = Wp + h * HSTRIDE;
    for (int q = tid; q < 3024; q += 512) {     // 112 rows x 27 uint2-quads
        const int o = q / 27, f0 = (q - o * 27) * 4;
        uint2 pp = {0u, 0u};
        if (f0 < 100) {
            if (o < 100) {
                float4 wv = *(const float4*)(Wh + o * 100 + f0);
                pp.x = pk2(wv.x, wv.y);
                pp.y = pk2(wv.z, wv.w);
            } else if (o == 100) {
                pp.x = pk2(sWS[f0], sWS[f0 + 1]);
                pp.y = pk2(sWS[f0 + 2], sWS[f0 + 3]);
            } else if (o == 101) {
                pp.x = pk2(sWD[f0], sWD[f0 + 1]);
                pp.y = pk2(sWD[f0 + 2], sWD[f0 + 3]);
            }
        }
        *(uint2*)(D + o * CST + f0) = pp;       // write covers ALL 108 cols
    }
    // zero exact 192-elem tail (12096..12287), no overrun (r23 bug fixed)
    for (int q = tid; q < 48; q += 512)
        *(uint2*)(D + 12096 + q * 4) = (uint2){0u, 0u};
}

// One block per t. 512 threads = 8 waves; waves 0..6 compute, wave 7
// staging+barriers only. LDS 49664 B -> 3 blocks/CU. (512,4) envelope.
// LDS: HT [112][108] bf16 @0 (FULLY zero-initialized: cols 104..107 must be
//      0 forever — r23 NaN fix); sas[112] @24192, sad[112] @24640; P [112][108]
//      @25088 (+384 B pad, zeroed at init for row-111 overhang reads).
// Async Wfill, free logits, low-pressure PVprep, direct reg->global epilogue.
// Fragment reads via 2x ds_read_b64 (ld8): 216 B stride -> ~4-way conflicts.
extern "C" __global__ void __launch_bounds__(512, 4)
gat23(const float* __restrict__ A, const unsigned short* __restrict__ Wp,
      const float* __restrict__ bias, float* __restrict__ out)
{
    extern __shared__ char smem[];
    unsigned short* HT = (unsigned short*)smem;
    float* sas  = (float*)(smem + SASOFF);
    float* sad  = (float*)(smem + SADOFF);
    unsigned short* P  = (unsigned short*)(smem + POFF);

    const int t    = blockIdx.x;
    const int tid  = threadIdx.x;      // 0..511
    const int w    = tid >> 6;         // 0..7
    const int l    = tid & 63;
    const int lr   = l & 15;
    const int lk   = l >> 4;
    const bool HASW = (w < 7);
    const int row  = HASW ? w : 6;
    const int j0   = row * 16 + 4 * lk;        // 0..108
    const bool JW  = HASW && (j0 < 104);
    const float* __restrict__ At = A + (size_t)t * 10000u;
    const f32x4 z4 = {0, 0, 0, 0};

    // ---- async Wfill(0) into P (issue first: hides under init+xf) ----
    {
        const char* Wg = (const char*)Wp;
#pragma unroll
        for (int k = 0; k < 3; ++k) {
            const int c0 = k * 512 + w * 64;
            if (c0 < HCHUNKS)
                __builtin_amdgcn_global_load_lds(
                    (const __attribute__((address_space(1))) unsigned*)(Wg + c0 * 16 + l * 16),
                    (__attribute__((address_space(3))) unsigned*)(smem + POFF + c0 * 16),
                    16, 0, 0);
        }
    }

    // ---- init: zero ALL of HT (1512 f32x4) + P pad (24 f32x4); stats ----
    for (int i = tid; i < 1512; i += 512) ((f32x4*)smem)[i] = z4;
    if (tid < 24) ((f32x4*)(smem + 49280))[tid] = z4;
    if (tid >= 64 && tid < 288) {
        const int s = tid - 64;
        float v = (s >= 100 && s < 112) ? -1e30f : 0.0f;
        ((float*)(smem + SASOFF))[s] = v;
    }

    // ---- xf: direct global loads of X = A_t^T fragments (waves 0..6) ----
    const int col = row * 16 + lr;
    const bool cOK = HASW && (col < 100);
    bf16x8 xf[4];
#pragma unroll
    for (int ks = 0; ks < 4; ++ks) {
        const bool kill = (ks == 3) && (lk != 0);
        const int koff = ks * 32 + lk * 8;
        u32x4 uv = {0u, 0u, 0u, 0u};
        if (cOK && !kill) {
#pragma unroll
            for (int jp = 0; jp < 4; ++jp) {
                const int f0 = koff + jp * 2;
                float a0 = (f0     < 100) ? At[f0 * 100 + col]       : 0.0f;
                float a1 = (f0 + 1 < 100) ? At[(f0 + 1) * 100 + col] : 0.0f;
                uv[jp] = pk2(a0, a1);
            }
        }
        xf[ks] = __builtin_bit_cast(bf16x8, uv);
    }
    __syncthreads();   // (b0): drains Wfill(0); init visible

    f32x4 acc[7];
#pragma unroll
    for (int c = 0; c < 7; ++c) acc[c] = z4;

    for (int h = 0; h < 4; ++h) {
        if (HASW) {
            // ---- GEMM-1, two N-halves; logits free from tile 6 ----
#pragma unroll
            for (int half = 0; half < 2; ++half) {
                const int ntn = half ? 3 : 4;
                f32x4 c[4];
#pragma unroll
                for (int cc = 0; cc < 4; ++cc) c[cc] = z4;
                __builtin_amdgcn_s_setprio(1);
#pragma unroll
                for (int ks = 0; ks < 4; ++ks) {
                    const int koff = ks * 32 + lk * 8;
                    bf16x8 b[4];
#pragma unroll
                    for (int bb = 0; bb < 4; ++bb)
                        if (bb < ntn)
                            b[bb] = ld8(P + ((half * 4 + bb) * 16 + lr) * CST + koff);
#pragma unroll
                    for (int bb = 0; bb < 4; ++bb)
                        if (bb < ntn)
                            c[bb] = __builtin_amdgcn_mfma_f32_16x16x32_bf16(xf[ks], b[bb], c[bb], 0, 0, 0);
                }
                __builtin_amdgcn_s_setprio(0);
#pragma unroll
                for (int bb = 0; bb < 4; ++bb)
                    if (bb < ntn) {
                        const int o = (half * 4 + bb) * 16 + lr;
                        if (JW) {
                            uint2 pp;
                            pp.x = pk2(c[bb].x, c[bb].y);
                            pp.y = pk2(c[bb].z, c[bb].w);
                            *(uint2*)(HT + o * CST + j0) = pp;
                        }
                    }
                if (half == 1) {
                    if (lr == 4 && j0 < 100) *(f32x4*)(sas + j0) = c[2];
                    if (lr == 5 && JW)       *(f32x4*)(sad + j0) = c[2];
                }
            }
        }
        __syncthreads();   // (c) HT + sas/sad ready; P idle

        // ---- async Wfill(h+1): hides under PVprep+PV ----
        if (h < 3) {
            const char* Wg = (const char*)(Wp + (h + 1) * HSTRIDE);
#pragma unroll
            for (int k = 0; k < 3; ++k) {
                const int c0 = k * 512 + w * 64;
                if (c0 < HCHUNKS)
                    __builtin_amdgcn_global_load_lds(
                        (const __attribute__((address_space(1))) unsigned*)(Wg + c0 * 16 + l * 16),
                        (__attribute__((address_space(3))) unsigned*)(smem + POFF + c0 * 16),
                        16, 0, 0);
            }
        }

        if (HASW) {
            // ---- PVprep: per-ks transient exps -> unnorm bf16 af; f32 sum ----
            const float adi = sad[row * 16 + lr];
            float sE = 0.0f;
            bf16x8 af[4];
#pragma unroll
            for (int ks = 0; ks < 4; ++ks) {
                const bool dead = (ks == 3) && (lk != 0);
                const int jb = dead ? 64 : ks * 32 + lk * 8;
                const f32x4 s0 = *(const f32x4*)(sas + jb);
                const f32x4 s1 = *(const f32x4*)(sas + jb + 4);
                float e0 = dead ? 0.0f : __expf(lrelu(adi + s0.x));
                float e1 = dead ? 0.0f : __expf(lrelu(adi + s0.y));
                float e2 = dead ? 0.0f : __expf(lrelu(adi + s0.z));
                float e3 = dead ? 0.0f : __expf(lrelu(adi + s0.w));
                float e4 = dead ? 0.0f : __expf(lrelu(adi + s1.x));
                float e5 = dead ? 0.0f : __expf(lrelu(adi + s1.y));
                float e6 = dead ? 0.0f : __expf(lrelu(adi + s1.z));
                float e7 = dead ? 0.0f : __expf(lrelu(adi + s1.w));
                sE += ((e0 + e1) + (e2 + e3)) + ((e4 + e5) + (e6 + e7));
                u32x4 uv;
                uv.x = pk2(e0, e1); uv.y = pk2(e2, e3);
                uv.z = pk2(e4, e5); uv.w = pk2(e6, e7);
                af[ks] = __builtin_bit_cast(bf16x8, uv);
            }
            sE += __shfl_xor(sE, 16);
            sE += __shfl_xor(sE, 32);
            const float invE = sE > 0.0f ? __builtin_amdgcn_rcpf(sE) : 0.0f;
#pragma unroll
            for (int ks = 0; ks < 4; ++ks) {
                u32x4 uv = __builtin_bit_cast(u32x4, af[ks]);
                uv.x = pk2(bflo(uv.x) * invE, bfhi(uv.x) * invE);
                uv.y = pk2(bflo(uv.y) * invE, bfhi(uv.y) * invE);
                uv.z = pk2(bflo(uv.z) * invE, bfhi(uv.z) * invE);
                uv.w = pk2(bflo(uv.w) * invE, bfhi(uv.w) * invE);
                af[ks] = __builtin_bit_cast(bf16x8, uv);
            }

            // ---- PV: acc += alpha * H ----
            __builtin_amdgcn_s_setprio(1);
#pragma unroll
            for (int half = 0; half < 2; ++half) {
                const int ntn = half ? 3 : 4;
#pragma unroll
                for (int ks = 0; ks < 4; ++ks) {
                    const int koff = ks * 32 + lk * 8;
                    bf16x8 b[4];
#pragma unroll
                    for (int bb = 0; bb < 4; ++bb)
                        if (bb < ntn)
                            b[bb] = ld8(HT + ((half * 4 + bb) * 16 + lr) * CST + koff);
#pragma unroll
                    for (int bb = 0; bb < 4; ++bb)
                        if (bb < ntn)
                            acc[half * 4 + bb] = __builtin_amdgcn_mfma_f32_16x16x32_bf16(
                                af[ks], b[bb], acc[half * 4 + bb], 0, 0, 0);
                }
            }
            __builtin_amdgcn_s_setprio(0);
        }
        __syncthreads();   // (d): drains Wfill(h+1); HT reusable
    }

    // ---- epilogue: DIRECT register->global stores ----
    if (HASW && j0 < 100) {
        float* __restrict__ outT = out + (size_t)t * 10000u;
#pragma unroll
        for (int tn = 0; tn < 7; ++tn) {
            const int o = tn * 16 + lr;
            if (o < 100) {
                const float b = bias[o];
                f32x4 v;
                v.x = lrelu(acc[tn].x * 0.25f + b) + ((j0 + 0) == o ? 1.0f : 0.0f);
                v.y = lrelu(acc[tn].y * 0.25f + b) + ((j0 + 1) == o ? 1.0f : 0.0f);
                v.z = lrelu(acc[tn].z * 0.25f + b) + ((j0 + 2) == o ? 1.0f : 0.0f);
                v.w = lrelu(acc[tn].w * 0.25f + b) + ((j0 + 3) == o ? 1.0f : 0.0f);
                *(f32x4*)(outT + o * 100 + j0) = v;
            }
        }
    }
}

extern "C" void kernel_launch(void* const* d_in, const int* in_sizes, int n_in,
                              void* d_out, int out_size, void* d_ws, size_t ws_size,
                              hipStream_t stream) {
    const float* A      = (const float*)d_in[0];
    const float* W      = (const float*)d_in[1];
    const float* attsrc = (const float*)d_in[2];
    const float* attdst = (const float*)d_in[3];
    const float* bias   = (const float*)d_in[4];
    float* outp = (float*)d_out;
    unsigned short* Wp = (unsigned short*)d_ws;   // 4*12288*2 = 98304 B

    const int T = in_sizes[0] / 10000;   // 1024

    prep_w<<<4, 512, 0, stream>>>(W, attsrc, attdst, Wp);

    const int smem_bytes = 49664;
    gat23<<<T, 512, smem_bytes, stream>>>(A, Wp, bias, outp);
}

// Round 25
// 64.119 us; speedup vs baseline: 3.1207x; 3.1207x over previous
//
#include <hip/hip_runtime.h>
#include <hip/hip_bf16.h>

typedef __attribute__((ext_vector_type(8))) short bf16x8;
typedef __attribute__((ext_vector_type(4))) float f32x4;
typedef __attribute__((ext_vector_type(4))) unsigned u32x4;

#define NEG 0.2f
#define CST 104         // bf16 elems per LDS row (208 B stride)
#define HSTRIDE 11648   // 112*104 bf16 elems per head in d_ws
#define POFF 24192      // P region byte offset in LDS

__device__ __forceinline__ float lrelu(float x) { return x >= 0.0f ? x : NEG * x; }

// packed pair via v_cvt_pk_bf16_f32 (RNE)
__device__ __forceinline__ unsigned pk2(float a, float b) {
    __hip_bfloat162 h = __float22bfloat162_rn(float2{a, b});
    unsigned r;
    __builtin_memcpy(&r, &h, sizeof(r));
    return r;
}
__device__ __forceinline__ float bflo(unsigned u) {
    unsigned v = u << 16; float f; __builtin_memcpy(&f, &v, 4); return f;
}
__device__ __forceinline__ float bfhi(unsigned u) {
    unsigned v = u & 0xffff0000u; float f; __builtin_memcpy(&f, &v, 4); return f;
}

// ---- prep (fast): Wp[h] = [112][104] bf16, exact LDS image ----
extern "C" __global__ void prep_w(const float* __restrict__ W,
                                  const float* __restrict__ att_src,
                                  const float* __restrict__ att_dst,
                                  unsigned short* __restrict__ Wp)
{
    __shared__ float red[2][4][128];
    __shared__ float sWS[128], sWD[128];
    const int h = blockIdx.x, tid = threadIdx.x;
    const int f = tid & 127, og = tid >> 7;
    const float* __restrict__ Wh = W + h * 10000;
    float ws = 0.0f, wd = 0.0f;
    if (f < 100) {
        for (int o = og * 25; o < og * 25 + 25; ++o) {
            float wv = Wh[o * 100 + f];
            ws = fmaf(att_src[h * 100 + o], wv, ws);
            wd = fmaf(att_dst[h * 100 + o], wv, wd);
        }
    }
    red[0][og][f] = ws;
    red[1][og][f] = wd;
    __syncthreads();
    if (tid < 256) {
        const int which = tid >> 7, ff = tid & 127;
        float s = (red[which][0][ff] + red[which][1][ff]) +
                  (red[which][2][ff] + red[which][3][ff]);
        (which ? sWD : sWS)[ff] = s;
    }
    __syncthreads();
    unsigned short* __restrict__ D = Wp + h * HSTRIDE;
    for (int q = tid; q < 2912; q += 512) {
        const int o = q / 26, f0 = (q - o * 26) * 4;
        uint2 pp = {0u, 0u};
        if (f0 < 100) {
            if (o < 100) {
                float4 wv = *(const float4*)(Wh + o * 100 + f0);
                pp.x = pk2(wv.x, wv.y);
                pp.y = pk2(wv.z, wv.w);
            } else if (o == 100) {
                pp.x = pk2(sWS[f0], sWS[f0 + 1]);
                pp.y = pk2(sWS[f0 + 2], sWS[f0 + 3]);
            } else if (o == 101) {
                pp.x = pk2(sWD[f0], sWD[f0 + 1]);
                pp.y = pk2(sWD[f0 + 2], sWD[f0 + 3]);
            }
        }
        *(uint2*)(D + o * CST + f0) = pp;
    }
}

// One block per t. 512 threads = 8 waves; waves 0..6 compute one 16-row tile
// each; wave 7 staging+barriers only. LDS 47744 B. (512,4) envelope (the only
// clean one — every expansion attempt in r8-r24 spilled or regressed).
// LDS: HT [112][104] bf16 @0; sas[112] @23296, sad[112] @23744 (f32,
//      sas[100..111] = -1e30); P [112][104] bf16 @24192 (+256 B pad).
// Async Wfill (global_load_lds, 16B) for head h+1 issued after barrier (c);
// loop-end barrier's vmcnt(0) drain lands it. 2 barriers/head. Logits free
// from GEMM-1 tile 6 (B-rows 100/101 = W^T att vectors). Low-pressure PVprep
// (per-ks transient exps -> bf16, bf16-domain rescale). Direct reg->global
// epilogue. BEST CONFIG: 64.0 us (13.9x vs f32 baseline).
extern "C" __global__ void __launch_bounds__(512, 4)
gat21(const float* __restrict__ A, const unsigned short* __restrict__ Wp,
      const float* __restrict__ bias, float* __restrict__ out)
{
    extern __shared__ char smem[];
    unsigned short* HT = (unsigned short*)smem;
    float* sas  = (float*)(smem + 23296);
    float* sad  = (float*)(smem + 23744);
    unsigned short* P  = (unsigned short*)(smem + POFF);

    const int t    = blockIdx.x;
    const int tid  = threadIdx.x;      // 0..511
    const int w    = tid >> 6;         // 0..7
    const int l    = tid & 63;
    const int lr   = l & 15;
    const int lk   = l >> 4;
    const bool HASW = (w < 7);
    const int row  = HASW ? w : 6;
    const int j0   = row * 16 + 4 * lk;        // 0..108
    const bool JW  = HASW && (j0 < 104);
    const float* __restrict__ At = A + (size_t)t * 10000u;
    const f32x4 z4 = {0, 0, 0, 0};

    // ---- init stats: sas[0..111] (pads -1e30), sad[0..111] = 0 ----
    if (tid < 224) {
        float v = (tid >= 100 && tid < 112) ? -1e30f : 0.0f;
        ((float*)(smem + 23296))[tid] = v;
    }

    // ---- async Wfill(0): fire-and-forget into P (drained at 1st barrier) ----
    {
        const char* Wg = (const char*)Wp;   // head 0
#pragma unroll
        for (int k = 0; k < 3; ++k) {
            const int c0 = k * 512 + w * 64;
            if (c0 < 1456)
                __builtin_amdgcn_global_load_lds(
                    (const __attribute__((address_space(1))) unsigned*)(Wg + c0 * 16 + l * 16),
                    (__attribute__((address_space(3))) unsigned*)(smem + POFF + c0 * 16),
                    16, 0, 0);
        }
    }

    // ---- xf: direct global loads of X = A_t^T fragments (waves 0..6) ----
    const int col = row * 16 + lr;
    const bool cOK = HASW && (col < 100);
    bf16x8 xf[4];
#pragma unroll
    for (int ks = 0; ks < 4; ++ks) {
        const bool kill = (ks == 3) && (lk != 0);
        const int koff = ks * 32 + lk * 8;
        u32x4 uv = {0u, 0u, 0u, 0u};
        if (cOK && !kill) {
#pragma unroll
            for (int jp = 0; jp < 4; ++jp) {
                const int f0 = koff + jp * 2;
                float a0 = (f0     < 100) ? At[f0 * 100 + col]       : 0.0f;
                float a1 = (f0 + 1 < 100) ? At[(f0 + 1) * 100 + col] : 0.0f;
                uv[jp] = pk2(a0, a1);
            }
        }
        xf[ks] = __builtin_bit_cast(bf16x8, uv);
    }
    __syncthreads();   // (b0): drains Wfill(0) vmcnt; stats visible

    f32x4 acc[7];
#pragma unroll
    for (int c = 0; c < 7; ++c) acc[c] = z4;

    for (int h = 0; h < 4; ++h) {
        if (HASW) {
            // ---- GEMM-1, two N-halves; logits free from tile 6 ----
#pragma unroll
            for (int half = 0; half < 2; ++half) {
                const int ntn = half ? 3 : 4;
                f32x4 c[4];
#pragma unroll
                for (int cc = 0; cc < 4; ++cc) c[cc] = z4;
                __builtin_amdgcn_s_setprio(1);
#pragma unroll
                for (int ks = 0; ks < 4; ++ks) {
                    const int koff = ks * 32 + lk * 8;   // A-side zero kills k-pad
                    bf16x8 b[4];
#pragma unroll
                    for (int bb = 0; bb < 4; ++bb)
                        if (bb < ntn)
                            b[bb] = *(const bf16x8*)(P + ((half * 4 + bb) * 16 + lr) * CST + koff);
#pragma unroll
                    for (int bb = 0; bb < 4; ++bb)
                        if (bb < ntn)
                            c[bb] = __builtin_amdgcn_mfma_f32_16x16x32_bf16(xf[ks], b[bb], c[bb], 0, 0, 0);
                }
                __builtin_amdgcn_s_setprio(0);
#pragma unroll
                for (int bb = 0; bb < 4; ++bb)
                    if (bb < ntn) {
                        const int o = (half * 4 + bb) * 16 + lr;
                        if (JW) {
                            uint2 pp;
                            pp.x = pk2(c[bb].x, c[bb].y);
                            pp.y = pk2(c[bb].z, c[bb].w);
                            *(uint2*)(HT + o * CST + j0) = pp;
                        }
                    }
                if (half == 1) {   // tile 6 C-cols 100/101 = a_s, a_d
                    if (lr == 4 && j0 < 100) *(f32x4*)(sas + j0) = c[2];
                    if (lr == 5 && JW)       *(f32x4*)(sad + j0) = c[2];
                }
            }
        }
        __syncthreads();   // (c) HT + sas/sad ready; P idle from here

        // ---- async Wfill(h+1) into P: latency hides under PVprep+PV ----
        if (h < 3) {
            const char* Wg = (const char*)(Wp + (h + 1) * HSTRIDE);
#pragma unroll
            for (int k = 0; k < 3; ++k) {
                const int c0 = k * 512 + w * 64;
                if (c0 < 1456)
                    __builtin_amdgcn_global_load_lds(
                        (const __attribute__((address_space(1))) unsigned*)(Wg + c0 * 16 + l * 16),
                        (__attribute__((address_space(3))) unsigned*)(smem + POFF + c0 * 16),
                        16, 0, 0);
            }
        }

        if (HASW) {
            // ---- PVprep: per-ks transient exps -> unnorm bf16 af; f32 sum ----
            const float adi = sad[row * 16 + lr];
            float sE = 0.0f;
            bf16x8 af[4];
#pragma unroll
            for (int ks = 0; ks < 4; ++ks) {
                const bool dead = (ks == 3) && (lk != 0);
                const int jb = dead ? 64 : ks * 32 + lk * 8;
                const f32x4 s0 = *(const f32x4*)(sas + jb);
                const f32x4 s1 = *(const f32x4*)(sas + jb + 4);
                float e0 = dead ? 0.0f : __expf(lrelu(adi + s0.x));
                float e1 = dead ? 0.0f : __expf(lrelu(adi + s0.y));
                float e2 = dead ? 0.0f : __expf(lrelu(adi + s0.z));
                float e3 = dead ? 0.0f : __expf(lrelu(adi + s0.w));
                float e4 = dead ? 0.0f : __expf(lrelu(adi + s1.x));
                float e5 = dead ? 0.0f : __expf(lrelu(adi + s1.y));
                float e6 = dead ? 0.0f : __expf(lrelu(adi + s1.z));
                float e7 = dead ? 0.0f : __expf(lrelu(adi + s1.w));
                sE += ((e0 + e1) + (e2 + e3)) + ((e4 + e5) + (e6 + e7));
                u32x4 uv;
                uv.x = pk2(e0, e1); uv.y = pk2(e2, e3);
                uv.z = pk2(e4, e5); uv.w = pk2(e6, e7);
                af[ks] = __builtin_bit_cast(bf16x8, uv);
            }
            sE += __shfl_xor(sE, 16);
            sE += __shfl_xor(sE, 32);
            const float invE = sE > 0.0f ? __builtin_amdgcn_rcpf(sE) : 0.0f;
#pragma unroll
            for (int ks = 0; ks < 4; ++ks) {   // bf16-domain rescale
                u32x4 uv = __builtin_bit_cast(u32x4, af[ks]);
                uv.x = pk2(bflo(uv.x) * invE, bfhi(uv.x) * invE);
                uv.y = pk2(bflo(uv.y) * invE, bfhi(uv.y) * invE);
                uv.z = pk2(bflo(uv.z) * invE, bfhi(uv.z) * invE);
                uv.w = pk2(bflo(uv.w) * invE, bfhi(uv.w) * invE);
                af[ks] = __builtin_bit_cast(bf16x8, uv);
            }

            // ---- PV: acc += alpha * H (direct C accumulation) ----
            __builtin_amdgcn_s_setprio(1);
#pragma unroll
            for (int half = 0; half < 2; ++half) {
                const int ntn = half ? 3 : 4;
#pragma unroll
                for (int ks = 0; ks < 4; ++ks) {
                    const int koff = ks * 32 + lk * 8;
                    bf16x8 b[4];
#pragma unroll
                    for (int bb = 0; bb < 4; ++bb)
                        if (bb < ntn)
                            b[bb] = *(const bf16x8*)(HT + ((half * 4 + bb) * 16 + lr) * CST + koff);
#pragma unroll
                    for (int bb = 0; bb < 4; ++bb)
                        if (bb < ntn)
                            acc[half * 4 + bb] = __builtin_amdgcn_mfma_f32_16x16x32_bf16(
                                af[ks], b[bb], acc[half * 4 + bb], 0, 0, 0);
                }
            }
            __builtin_amdgcn_s_setprio(0);
        }
        __syncthreads();   // (d): drains Wfill(h+1) -> P ready; HT reusable
    }

    // ---- epilogue: DIRECT register->global stores (no LDS round-trip) ----
    if (HASW && j0 < 100) {
        float* __restrict__ outT = out + (size_t)t * 10000u;
#pragma unroll
        for (int tn = 0; tn < 7; ++tn) {
            const int o = tn * 16 + lr;
            if (o < 100) {
                const float b = bias[o];
                f32x4 v;
                v.x = lrelu(acc[tn].x * 0.25f + b) + ((j0 + 0) == o ? 1.0f : 0.0f);
                v.y = lrelu(acc[tn].y * 0.25f + b) + ((j0 + 1) == o ? 1.0f : 0.0f);
                v.z = lrelu(acc[tn].z * 0.25f + b) + ((j0 + 2) == o ? 1.0f : 0.0f);
                v.w = lrelu(acc[tn].w * 0.25f + b) + ((j0 + 3) == o ? 1.0f : 0.0f);
                *(f32x4*)(outT + o * 100 + j0) = v;
            }
        }
    }
}

extern "C" void kernel_launch(void* const* d_in, const int* in_sizes, int n_in,
                              void* d_out, int out_size, void* d_ws, size_t ws_size,
                              hipStream_t stream) {
    const float* A      = (const float*)d_in[0];
    const float* W      = (const float*)d_in[1];
    const float* attsrc = (const float*)d_in[2];
    const float* attdst = (const float*)d_in[3];
    const float* bias   = (const float*)d_in[4];
    float* outp = (float*)d_out;
    unsigned short* Wp = (unsigned short*)d_ws;   // 4*11648*2 = 93184 B

    const int T = in_sizes[0] / 10000;   // 1024

    prep_w<<<4, 512, 0, stream>>>(W, attsrc, attdst, Wp);

    const int smem_bytes = 47744;
    gat21<<<T, 512, smem_bytes, stream>>>(A, Wp, bias, outp);
}